// Round 4
// baseline (18359.399 us; speedup 1.0000x reference)
//
#include <hip/hip_runtime.h>
#include <hip/hip_fp16.h>

#define B_   128
#define L_   1024
#define DIN  64
#define H_   512
#define DOUT 64

typedef _Float16 half8 __attribute__((ext_vector_type(8)));
typedef float    f32x4 __attribute__((ext_vector_type(4)));

#define FSTR 16            // flag stride in ints (64B)
#define SPIN_CAP (1<<19)   // busy-poll cap: protocol bug -> wrong answer, not hang

#define MFMA16(a,b,c) __builtin_amdgcn_mfma_f32_16x16x32_f16((a),(b),(c),0,0,0)

// ---------------- flag init (re-run every launch -> graph-replay safe) ----------------
__global__ void k_init_flags(int* flags) {
    int i = threadIdx.x;
    if (i < 64) flags[i * FSTR] = -1;
}

// ---------------- cast weights to f16 + bias sums ----------------
__global__ void k_prep_w(const float* __restrict__ whh0, const float* __restrict__ wih1,
                         const float* __restrict__ whh1, const float* __restrict__ wout,
                         const float* __restrict__ bih0, const float* __restrict__ bhh0,
                         const float* __restrict__ bih1, const float* __restrict__ bhh1,
                         _Float16* __restrict__ o0, _Float16* __restrict__ o1,
                         _Float16* __restrict__ o2, _Float16* __restrict__ o3,
                         float* __restrict__ b0s, float* __restrict__ b1s) {
    const int NW = H_ * H_;
    const int total = 3 * NW + DOUT * H_ + 2 * H_;
    int i  = blockIdx.x * blockDim.x + threadIdx.x;
    int st = gridDim.x * blockDim.x;
    for (; i < total; i += st) {
        if      (i < NW)            o0[i]          = (_Float16)whh0[i];
        else if (i < 2 * NW)        o1[i - NW]     = (_Float16)wih1[i - NW];
        else if (i < 3 * NW)        o2[i - 2 * NW] = (_Float16)whh1[i - 2 * NW];
        else if (i < 3 * NW + DOUT * H_) o3[i - 3 * NW] = (_Float16)wout[i - 3 * NW];
        else if (i < 3 * NW + DOUT * H_ + H_) {
            int j = i - (3 * NW + DOUT * H_);
            b0s[j] = bih0[j] + bhh0[j];
        } else {
            int j = i - (3 * NW + DOUT * H_ + H_);
            b1s[j] = bih1[j] + bhh1[j];
        }
    }
}

// ---------------- wcomb[g][d] = sum_h W_ih0[g][h] * W_in[h][d] (proj_in folded in) ----------------
__global__ void k_wcomb(const float* __restrict__ wih0, const float* __restrict__ win,
                        _Float16* __restrict__ o) {
    int g = blockIdx.x;    // 512
    int d = threadIdx.x;   // 64
    float acc = 0.f;
    for (int h = 0; h < H_; ++h)
        acc += wih0[g * H_ + h] * win[h * DIN + d];
    o[g * DIN + d] = (_Float16)acc;
}

// ---------------- coherent (device-point) helpers ----------------
__device__ __forceinline__ void spin_rel(const int* fp, int tgt) {
    if (!fp) return;
    int it = 0;
    while (__hip_atomic_load(fp, __ATOMIC_RELAXED, __HIP_MEMORY_SCOPE_AGENT) < tgt) {
        if (++it > SPIN_CAP) break;   // busy poll; probe period ~= load latency
    }
}

__device__ __forceinline__ uint64_t ld8c(const void* p) {
    return __hip_atomic_load((const uint64_t*)p, __ATOMIC_RELAXED, __HIP_MEMORY_SCOPE_AGENT);
}

__device__ __forceinline__ half8 ldh8c(const _Float16* p) {
    union { uint64_t q[2]; half8 h; } u;
    u.q[0] = ld8c(p);
    u.q[1] = ld8c(p + 4);
    return u.h;
}

__device__ __forceinline__ void st2c(_Float16* p, float v) {
    _Float16 h = (_Float16)v;
    __hip_atomic_store((unsigned short*)p, __builtin_bit_cast(unsigned short, h),
                       __ATOMIC_RELAXED, __HIP_MEMORY_SCOPE_AGENT);
}

__device__ __forceinline__ void flag_pub(int* fp, int t) {
    __hip_atomic_store(fp, t, __ATOMIC_RELAXED, __HIP_MEMORY_SCOPE_AGENT);
}

__device__ __forceinline__ float tanh_fast(float v) {
    float e = __expf(2.f * v);
    return 1.f - 2.f / (e + 1.f);
}

// ---------------- fused persistent pipeline ----------------
// 56 blocks x 512 threads: g = bid&7, role = bid>>3 in [0,7):
//   role 0,1 : L0 block d=role, cols [d*256, d*256+256)
//   role 2..5: L1 block e=role-2, cols [e*128, e*128+128)
//   role 6   : G3 output projection (waves 0-3 compute)
// Own h-slice round-trips through LDS; remote slices via device-coherent (sc) loads.
// flags[g*7 + idx]: idx 0,1=L0; 2..5=L1; 6=G3; value = last completed step.
__global__ __launch_bounds__(512, 2)
void k_pipe(const float* __restrict__ u,
            const _Float16* __restrict__ wcomb,   // [512][64]
            const _Float16* __restrict__ whh0w,   // [512][512]
            const float* __restrict__ b0s,
            const _Float16* __restrict__ wih1w,   // [512][512]
            const _Float16* __restrict__ whh1w,   // [512][512]
            const float* __restrict__ b1s,
            const _Float16* __restrict__ woutw,   // [64][512]
            float* __restrict__ out,              // [B_*L_][64] fp32
            _Float16* __restrict__ hx0,           // [8][4][16][512]
            _Float16* __restrict__ hx1,           // [8][4][16][512]
            int* __restrict__ flags) {
    const int bid = blockIdx.x;
    const int g = bid & 7, role = bid >> 3;
    const int tid = threadIdx.x;
    const int l = tid & 63, w = tid >> 6;          // 8 waves
    const int l15 = l & 15, lg = l >> 4, kofs = lg * 8;
    const int b0 = g * 16;
    _Float16* hx0g = hx0 + (size_t)g * (4 * 16 * H_);
    _Float16* hx1g = hx1 + (size_t)g * (4 * 16 * H_);
    int* fbase = flags + g * 7 * FSTR;

    __shared__ _Float16 hl[16][264];   // own-slice staging (+8 pad: 2-way banks, free)

    if (role < 2) {
        // ================= L0 =================
        const int d = role;
        const int col0 = d * 256 + w * 32;
        half8 whf[2][16], wcf[2][2];
#pragma unroll
        for (int nt = 0; nt < 2; ++nt) {
            const int n = col0 + nt * 16 + l15;
#pragma unroll
            for (int kt = 0; kt < 16; ++kt)
                whf[nt][kt] = *(const half8*)(whh0w + (size_t)n * H_ + kt * 32 + kofs);
#pragma unroll
            for (int kt = 0; kt < 2; ++kt)
                wcf[nt][kt] = *(const half8*)(wcomb + (size_t)n * DIN + kt * 32 + kofs);
        }
        const float bv0 = b0s[col0 + l15], bv1 = b0s[col0 + 16 + l15];
        int* myflag = fbase + d * FSTR;
        const int* pollp = nullptr; int polld = 0;
        if (tid == 0)      { pollp = fbase + (1 - d) * FSTR;   polld = 1; }  // partner L0
        else if (tid <= 4) { pollp = fbase + (1 + tid) * FSTR; polld = 4; }  // L1 consumers

        const int pr0 = (1 - d) * 8, ow0 = d * 8;   // remote / own kt ranges

        for (int t = 0; t < L_; ++t) {
            // phase 1: u part (independent of all sync)
            const float* up = u + ((size_t)(b0 + l15) * L_ + t) * DIN + kofs;
            f32x4 u0a = *(const f32x4*)(up);
            f32x4 u0b = *(const f32x4*)(up + 4);
            f32x4 u1a = *(const f32x4*)(up + 32);
            f32x4 u1b = *(const f32x4*)(up + 36);
            half8 ua[2];
#pragma unroll
            for (int j = 0; j < 4; ++j) {
                ua[0][j] = (_Float16)u0a[j]; ua[0][4 + j] = (_Float16)u0b[j];
                ua[1][j] = (_Float16)u1a[j]; ua[1][4 + j] = (_Float16)u1b[j];
            }
            f32x4 acc0 = (f32x4){bv0, bv0, bv0, bv0};
            f32x4 acc1 = (f32x4){bv1, bv1, bv1, bv1};
#pragma unroll
            for (int kt = 0; kt < 2; ++kt) {
                acc0 = MFMA16(ua[kt], wcf[0][kt], acc0);
                acc1 = MFMA16(ua[kt], wcf[1][kt], acc1);
            }
            // phase 2: wait
            spin_rel(pollp, t - polld);
            __syncthreads();
            asm volatile("" ::: "memory");
            // phase 3: h0_{t-1}: issue remote, chain own-LDS, chain remote
            if (t > 0) {
                const _Float16* hp = hx0g + (size_t)((t - 1) & 3) * (16 * H_)
                                   + (size_t)l15 * H_ + kofs;
                half8 hr[8];
#pragma unroll
                for (int j = 0; j < 8; ++j) hr[j] = ldh8c(hp + (pr0 + j) * 32);
#pragma unroll
                for (int j = 0; j < 8; ++j) {
                    half8 ho = *(const half8*)&hl[l15][j * 32 + kofs];
                    acc0 = MFMA16(ho, whf[0][ow0 + j], acc0);
                    acc1 = MFMA16(ho, whf[1][ow0 + j], acc1);
                }
#pragma unroll
                for (int j = 0; j < 8; ++j) {
                    acc0 = MFMA16(hr[j], whf[0][pr0 + j], acc0);
                    acc1 = MFMA16(hr[j], whf[1][pr0 + j], acc1);
                }
            }
            // phase 4: tanh
            float th0[4], th1[4];
#pragma unroll
            for (int r = 0; r < 4; ++r) { th0[r] = tanh_fast(acc0[r]); th1[r] = tanh_fast(acc1[r]); }
            __syncthreads();   // all LDS reads (phase 3) done before overwrite
            // phase 5: write own slice (LDS + global) and publish
            _Float16* hq = hx0g + (size_t)(t & 3) * (16 * H_);
#pragma unroll
            for (int r = 0; r < 4; ++r) {
                const int m = lg * 4 + r;
                const int nl0 = (col0 - d * 256) + l15;
                hl[m][nl0]      = (_Float16)th0[r];
                hl[m][nl0 + 16] = (_Float16)th1[r];
                st2c(&hq[(size_t)m * H_ + col0 + l15],      th0[r]);
                st2c(&hq[(size_t)m * H_ + col0 + 16 + l15], th1[r]);
            }
            asm volatile("s_waitcnt vmcnt(0)" ::: "memory");
            __syncthreads();
            if (tid == 0) flag_pub(myflag, t);
        }
    } else if (role < 6) {
        // ================= L1 =================
        const int e = role - 2;
        const int col0 = e * 128 + w * 16;
        const int n = col0 + l15;
        half8 wif[16], whf[16];
#pragma unroll
        for (int kt = 0; kt < 16; ++kt) {
            wif[kt] = *(const half8*)(wih1w + (size_t)n * H_ + kt * 32 + kofs);
            whf[kt] = *(const half8*)(whh1w + (size_t)n * H_ + kt * 32 + kofs);
        }
        const float bv = b1s[n];
        int* myflag = fbase + (2 + e) * FSTR;
        // phase-A pollers: 3 L1 partners (lag 1) + G3 (lag 4)
        const int* pollA = nullptr; int lagA = 0;
        if (tid < 3)       { pollA = fbase + (2 + (tid < e ? tid : tid + 1)) * FSTR; lagA = 1; }
        else if (tid == 3) { pollA = fbase + 6 * FSTR;                               lagA = 4; }
        // phase-B pollers: 2 L0 flags (lag 0)
        const int* pollB = (tid < 2) ? fbase + tid * FSTR : nullptr;

        const int ow0 = e * 4;   // own kt range [ow0, ow0+4)

        for (int t = 0; t < L_; ++t) {
            // phase A: h1_{t-1} (slack-rich: partners published at t-1)
            spin_rel(pollA, t - lagA);
            __syncthreads();
            asm volatile("" ::: "memory");
            f32x4 acch = (f32x4){0.f, 0.f, 0.f, 0.f};
            if (t > 0) {
                const _Float16* h1p = hx1g + (size_t)((t - 1) & 3) * (16 * H_)
                                    + (size_t)l15 * H_ + kofs;
                half8 hr[12];
                int ri = 0;
#pragma unroll
                for (int kt = 0; kt < 16; ++kt)
                    if ((kt >> 2) != e) hr[ri++] = ldh8c(h1p + kt * 32);
#pragma unroll
                for (int j = 0; j < 4; ++j) {
                    half8 ho = *(const half8*)&hl[l15][j * 32 + kofs];
                    acch = MFMA16(ho, whf[ow0 + j], acch);
                }
                ri = 0;
#pragma unroll
                for (int kt = 0; kt < 16; ++kt)
                    if ((kt >> 2) != e) acch = MFMA16(hr[ri++], whf[kt], acch);
            }
            // phase B: h0_t (lag-0 cross feed)
            spin_rel(pollB, t);
            __syncthreads();
            asm volatile("" ::: "memory");
            f32x4 accx = (f32x4){bv, bv, bv, bv};
            {
                const _Float16* h0p = hx0g + (size_t)(t & 3) * (16 * H_)
                                    + (size_t)l15 * H_ + kofs;
                half8 h0a[16];
#pragma unroll
                for (int kt = 0; kt < 16; ++kt) h0a[kt] = ldh8c(h0p + kt * 32);
#pragma unroll
                for (int kt = 0; kt < 16; ++kt) accx = MFMA16(h0a[kt], wif[kt], accx);
            }
            // tanh + writes (phase-B barrier already separates prior LDS reads)
            float th[4];
#pragma unroll
            for (int r = 0; r < 4; ++r) th[r] = tanh_fast(accx[r] + acch[r]);
            _Float16* hq = hx1g + (size_t)(t & 3) * (16 * H_);
#pragma unroll
            for (int r = 0; r < 4; ++r) {
                const int m = lg * 4 + r;
                hl[m][w * 16 + l15] = (_Float16)th[r];
                st2c(&hq[(size_t)m * H_ + n], th[r]);
            }
            asm volatile("s_waitcnt vmcnt(0)" ::: "memory");
            __syncthreads();
            if (tid == 0) flag_pub(myflag, t);
        }
    } else {
        // ================= G3 (output projection; waves 0-3 compute) =================
        const int n = (w & 3) * 16 + l15;
        half8 wof[16];
        if (w < 4) {
#pragma unroll
            for (int kt = 0; kt < 16; ++kt)
                wof[kt] = *(const half8*)(woutw + (size_t)n * H_ + kt * 32 + kofs);
        }
        int* myflag = fbase + 6 * FSTR;
        const int* pollp = (tid < 4) ? fbase + (2 + tid) * FSTR : nullptr;

        for (int t = 0; t < L_; ++t) {
            spin_rel(pollp, t);
            __syncthreads();
            asm volatile("" ::: "memory");
            f32x4 acc = (f32x4){0.f, 0.f, 0.f, 0.f};
            if (w < 4) {
                const _Float16* h1p = hx1g + (size_t)(t & 3) * (16 * H_)
                                    + (size_t)l15 * H_ + kofs;
                half8 a[16];
#pragma unroll
                for (int kt = 0; kt < 16; ++kt) a[kt] = ldh8c(h1p + kt * 32);
#pragma unroll
                for (int kt = 0; kt < 16; ++kt) acc = MFMA16(a[kt], wof[kt], acc);
            }
            __syncthreads();                       // all h1_t consumed
            if (tid == 0) flag_pub(myflag, t);     // release slot BEFORE out stores
            if (w < 4) {
#pragma unroll
                for (int r = 0; r < 4; ++r)
                    out[((size_t)(b0 + lg * 4 + r) * L_ + t) * DOUT + n] = acc[r];
            }
        }
    }
}

// ---------------- launch ----------------
extern "C" void kernel_launch(void* const* d_in, const int* in_sizes, int n_in,
                              void* d_out, int out_size, void* d_ws, size_t ws_size,
                              hipStream_t stream) {
    const float* u    = (const float*)d_in[0];
    const float* Win  = (const float*)d_in[1];
    const float* Wih0 = (const float*)d_in[2];
    const float* Whh0 = (const float*)d_in[3];
    const float* bih0 = (const float*)d_in[4];
    const float* bhh0 = (const float*)d_in[5];
    const float* Wih1 = (const float*)d_in[6];
    const float* Whh1 = (const float*)d_in[7];
    const float* bih1 = (const float*)d_in[8];
    const float* bhh1 = (const float*)d_in[9];
    const float* Wout = (const float*)d_in[10];
    (void)in_sizes; (void)n_in; (void)out_size; (void)ws_size;

    char* ws = (char*)d_ws;
    size_t off = 0;
    auto alloc = [&](size_t bytes) {
        char* p = ws + off;
        off += (bytes + 255) & ~(size_t)255;
        return p;
    };
    // total workspace ~2.7 MB
    _Float16* wcomb = (_Float16*)alloc((size_t)H_ * DIN * 2);
    _Float16* whh0h = (_Float16*)alloc((size_t)H_ * H_ * 2);
    _Float16* wih1h = (_Float16*)alloc((size_t)H_ * H_ * 2);
    _Float16* whh1h = (_Float16*)alloc((size_t)H_ * H_ * 2);
    _Float16* wouth = (_Float16*)alloc((size_t)DOUT * H_ * 2);
    float*    b0s   = (float*)alloc(H_ * 4);
    float*    b1s   = (float*)alloc(H_ * 4);
    _Float16* hx0   = (_Float16*)alloc((size_t)8 * 4 * 16 * H_ * 2);
    _Float16* hx1   = (_Float16*)alloc((size_t)8 * 4 * 16 * H_ * 2);
    int*      flags = (int*)alloc(64 * FSTR * 4);

    k_init_flags<<<1, 64, 0, stream>>>(flags);
    k_prep_w<<<1024, 256, 0, stream>>>(Whh0, Wih1, Whh1, Wout, bih0, bhh0, bih1, bhh1,
                                       whh0h, wih1h, whh1h, wouth, b0s, b1s);
    k_wcomb<<<512, 64, 0, stream>>>(Wih0, Win, wcomb);

    k_pipe<<<56, 512, 0, stream>>>(u, wcomb, whh0h, b0s, wih1h, whh1h, b1s, wouth,
                                   (float*)d_out, hx0, hx1, flags);
}

// Round 5
// 5104.181 us; speedup vs baseline: 3.5969x; 3.5969x over previous
//
#include <hip/hip_runtime.h>
#include <hip/hip_fp16.h>

#define B_   128
#define L_   1024
#define DIN  64
#define H_   512
#define DOUT 64

typedef _Float16 half8 __attribute__((ext_vector_type(8)));
typedef float    f32x4 __attribute__((ext_vector_type(4)));

#define FSTR 16            // flag stride in ints (64B)
#define SPIN_CAP (1<<17)   // busy-poll cap: protocol bug -> wrong answer, not hang

#define MFMA16(a,b,c) __builtin_amdgcn_mfma_f32_16x16x32_f16((a),(b),(c),0,0,0)
// pin a value into a VGPR tuple: compiler can no longer sink/remat the load into the loop
#define PINH8(x) asm volatile("" : "+v"(x))

// ---------------- flag init (re-run every launch -> graph-replay safe) ----------------
__global__ void k_init_flags(int* flags) {
    int i = threadIdx.x;
    if (i < 128) flags[i * FSTR] = -1;
}

// ---------------- cast weights to f16 + bias sums ----------------
__global__ void k_prep_w(const float* __restrict__ whh0, const float* __restrict__ wih1,
                         const float* __restrict__ whh1, const float* __restrict__ wout,
                         const float* __restrict__ bih0, const float* __restrict__ bhh0,
                         const float* __restrict__ bih1, const float* __restrict__ bhh1,
                         _Float16* __restrict__ o0, _Float16* __restrict__ o1,
                         _Float16* __restrict__ o2, _Float16* __restrict__ o3,
                         float* __restrict__ b0s, float* __restrict__ b1s) {
    const int NW = H_ * H_;
    const int total = 3 * NW + DOUT * H_ + 2 * H_;
    int i  = blockIdx.x * blockDim.x + threadIdx.x;
    int st = gridDim.x * blockDim.x;
    for (; i < total; i += st) {
        if      (i < NW)            o0[i]          = (_Float16)whh0[i];
        else if (i < 2 * NW)        o1[i - NW]     = (_Float16)wih1[i - NW];
        else if (i < 3 * NW)        o2[i - 2 * NW] = (_Float16)whh1[i - 2 * NW];
        else if (i < 3 * NW + DOUT * H_) o3[i - 3 * NW] = (_Float16)wout[i - 3 * NW];
        else if (i < 3 * NW + DOUT * H_ + H_) {
            int j = i - (3 * NW + DOUT * H_);
            b0s[j] = bih0[j] + bhh0[j];
        } else {
            int j = i - (3 * NW + DOUT * H_ + H_);
            b1s[j] = bih1[j] + bhh1[j];
        }
    }
}

// ---------------- wcomb[g][d] = sum_h W_ih0[g][h] * W_in[h][d] (proj_in folded in) ----------------
__global__ void k_wcomb(const float* __restrict__ wih0, const float* __restrict__ win,
                        _Float16* __restrict__ o) {
    int g = blockIdx.x;    // 512
    int d = threadIdx.x;   // 64
    float acc = 0.f;
    for (int h = 0; h < H_; ++h)
        acc += wih0[g * H_ + h] * win[h * DIN + d];
    o[g * DIN + d] = (_Float16)acc;
}

// ---------------- coherent (L3-point) helpers ----------------
__device__ __forceinline__ void spin_rel(const int* fp, int tgt) {
    if (!fp) return;
    int it = 0;
    while (__hip_atomic_load(fp, __ATOMIC_RELAXED, __HIP_MEMORY_SCOPE_AGENT) < tgt) {
        if (++it > SPIN_CAP) break;
    }
}

// 16 x 16B coherent loads from base + kt*64B, one internal vmcnt(0). Outputs valid at asm end.
__device__ __forceinline__ void ld_frags16_sc(const _Float16* base, half8 f[16]) {
    asm volatile(
        "global_load_dwordx4 %0, %16, off sc0 sc1\n\t"
        "global_load_dwordx4 %1, %16, off offset:64 sc0 sc1\n\t"
        "global_load_dwordx4 %2, %16, off offset:128 sc0 sc1\n\t"
        "global_load_dwordx4 %3, %16, off offset:192 sc0 sc1\n\t"
        "global_load_dwordx4 %4, %16, off offset:256 sc0 sc1\n\t"
        "global_load_dwordx4 %5, %16, off offset:320 sc0 sc1\n\t"
        "global_load_dwordx4 %6, %16, off offset:384 sc0 sc1\n\t"
        "global_load_dwordx4 %7, %16, off offset:448 sc0 sc1\n\t"
        "global_load_dwordx4 %8, %16, off offset:512 sc0 sc1\n\t"
        "global_load_dwordx4 %9, %16, off offset:576 sc0 sc1\n\t"
        "global_load_dwordx4 %10, %16, off offset:640 sc0 sc1\n\t"
        "global_load_dwordx4 %11, %16, off offset:704 sc0 sc1\n\t"
        "global_load_dwordx4 %12, %16, off offset:768 sc0 sc1\n\t"
        "global_load_dwordx4 %13, %16, off offset:832 sc0 sc1\n\t"
        "global_load_dwordx4 %14, %16, off offset:896 sc0 sc1\n\t"
        "global_load_dwordx4 %15, %16, off offset:960 sc0 sc1\n\t"
        "s_waitcnt vmcnt(0)"
        : "=&v"(f[0]), "=&v"(f[1]), "=&v"(f[2]), "=&v"(f[3]),
          "=&v"(f[4]), "=&v"(f[5]), "=&v"(f[6]), "=&v"(f[7]),
          "=&v"(f[8]), "=&v"(f[9]), "=&v"(f[10]), "=&v"(f[11]),
          "=&v"(f[12]), "=&v"(f[13]), "=&v"(f[14]), "=&v"(f[15])
        : "v"(base)
        : "memory");
}

// same, but no wait (used as first batch of two; the waiting batch's vmcnt(0) covers it)
__device__ __forceinline__ void ld_frags16_sc_nowait(const _Float16* base, half8 f[16]) {
    asm volatile(
        "global_load_dwordx4 %0, %16, off sc0 sc1\n\t"
        "global_load_dwordx4 %1, %16, off offset:64 sc0 sc1\n\t"
        "global_load_dwordx4 %2, %16, off offset:128 sc0 sc1\n\t"
        "global_load_dwordx4 %3, %16, off offset:192 sc0 sc1\n\t"
        "global_load_dwordx4 %4, %16, off offset:256 sc0 sc1\n\t"
        "global_load_dwordx4 %5, %16, off offset:320 sc0 sc1\n\t"
        "global_load_dwordx4 %6, %16, off offset:384 sc0 sc1\n\t"
        "global_load_dwordx4 %7, %16, off offset:448 sc0 sc1\n\t"
        "global_load_dwordx4 %8, %16, off offset:512 sc0 sc1\n\t"
        "global_load_dwordx4 %9, %16, off offset:576 sc0 sc1\n\t"
        "global_load_dwordx4 %10, %16, off offset:640 sc0 sc1\n\t"
        "global_load_dwordx4 %11, %16, off offset:704 sc0 sc1\n\t"
        "global_load_dwordx4 %12, %16, off offset:768 sc0 sc1\n\t"
        "global_load_dwordx4 %13, %16, off offset:832 sc0 sc1\n\t"
        "global_load_dwordx4 %14, %16, off offset:896 sc0 sc1\n\t"
        "global_load_dwordx4 %15, %16, off offset:960 sc0 sc1"
        : "=&v"(f[0]), "=&v"(f[1]), "=&v"(f[2]), "=&v"(f[3]),
          "=&v"(f[4]), "=&v"(f[5]), "=&v"(f[6]), "=&v"(f[7]),
          "=&v"(f[8]), "=&v"(f[9]), "=&v"(f[10]), "=&v"(f[11]),
          "=&v"(f[12]), "=&v"(f[13]), "=&v"(f[14]), "=&v"(f[15])
        : "v"(base)
        : "memory");
}

// re-bind 16 frags after a waiting asm: volatile-ordered => uses happen after the vmcnt(0)
#define PIN16(f) asm volatile("" : "+v"(f[0]), "+v"(f[1]), "+v"(f[2]), "+v"(f[3]), \
    "+v"(f[4]), "+v"(f[5]), "+v"(f[6]), "+v"(f[7]), "+v"(f[8]), "+v"(f[9]), \
    "+v"(f[10]), "+v"(f[11]), "+v"(f[12]), "+v"(f[13]), "+v"(f[14]), "+v"(f[15]))

__device__ __forceinline__ void st2c(_Float16* p, float v) {
    _Float16 h = (_Float16)v;
    __hip_atomic_store((unsigned short*)p, __builtin_bit_cast(unsigned short, h),
                       __ATOMIC_RELAXED, __HIP_MEMORY_SCOPE_AGENT);
}

__device__ __forceinline__ void flag_pub(int* fp, int t) {
    __hip_atomic_store(fp, t, __ATOMIC_RELAXED, __HIP_MEMORY_SCOPE_AGENT);
}

__device__ __forceinline__ float tanh_fast(float v) {
    float e = __expf(2.f * v);
    return 1.f - 2.f / (e + 1.f);
}

// ---------------- fused persistent pipeline (round-2 topology, VGPR-pinned weights) ----------------
// grid = 104 blocks x 256 thr: g = bid&7, role = bid>>3.
//   role 0..3  : L0, col slice 128*role
//   role 4..11 : L1, col slice 64*(role-4)
//   role 12    : G3 output projection
// h via depth-4 slot buffers hx0/hx1 [8][4][16][512] f16 (sc0 sc1 ops, L3 coherence point).
__global__ __launch_bounds__(256, 1)
void k_pipeline(const float* __restrict__ u,
                const _Float16* __restrict__ wcomb,   // [512][64]
                const _Float16* __restrict__ whh0w,   // [512][512]
                const float* __restrict__ b0s,
                const _Float16* __restrict__ wih1w,   // [512][512]
                const _Float16* __restrict__ whh1w,   // [512][512]
                const float* __restrict__ b1s,
                const _Float16* __restrict__ woutw,   // [64][512]
                float* __restrict__ out,              // [B_*L_][64] fp32
                _Float16* __restrict__ hx0,
                _Float16* __restrict__ hx1,
                int* __restrict__ flags) {
    const int bid = blockIdx.x;
    const int g = bid & 7, role = bid >> 3;
    const int tid = threadIdx.x;
    const int l = tid & 63, w = tid >> 6;
    const int l15 = l & 15, lg = l >> 4, kofs = lg * 8;
    const int b0 = g * 16;
    _Float16* hx0g = hx0 + (size_t)g * (4 * 16 * H_);
    _Float16* hx1g = hx1 + (size_t)g * (4 * 16 * H_);

    if (role < 4) {
        // ================= L0 =================
        const int s = role;
        const int col0 = s * 128 + w * 32;
        half8 whf[2][16], wcf[2][2];
#pragma unroll
        for (int nt = 0; nt < 2; ++nt) {
            const int n = col0 + nt * 16 + l15;
#pragma unroll
            for (int kt = 0; kt < 16; ++kt) {
                whf[nt][kt] = *(const half8*)(whh0w + (size_t)n * H_ + kt * 32 + kofs);
                PINH8(whf[nt][kt]);
            }
#pragma unroll
            for (int kt = 0; kt < 2; ++kt) {
                wcf[nt][kt] = *(const half8*)(wcomb + (size_t)n * DIN + kt * 32 + kofs);
                PINH8(wcf[nt][kt]);
            }
        }
        const float bv0 = b0s[col0 + l15], bv1 = b0s[col0 + 16 + l15];
        int* myflag = flags + (g * 4 + s) * FSTR;
        const int* pollp = (tid < 4)  ? flags + (g * 4 + tid) * FSTR
                         : (tid < 12) ? flags + (32 + g * 8 + (tid - 4)) * FSTR : nullptr;
        const int polld = (tid < 4) ? 1 : 4;

        for (int t = 0; t < L_; ++t) {
            // u fragment (independent of sync; normal cached loads)
            const float* up = u + ((size_t)(b0 + l15) * L_ + t) * DIN + kofs;
            f32x4 u0a = *(const f32x4*)(up);
            f32x4 u0b = *(const f32x4*)(up + 4);
            f32x4 u1a = *(const f32x4*)(up + 32);
            f32x4 u1b = *(const f32x4*)(up + 36);
            half8 ua[2];
#pragma unroll
            for (int j = 0; j < 4; ++j) {
                ua[0][j] = (_Float16)u0a[j]; ua[0][4 + j] = (_Float16)u0b[j];
                ua[1][j] = (_Float16)u1a[j]; ua[1][4 + j] = (_Float16)u1b[j];
            }
            spin_rel(pollp, t - polld);
            __syncthreads();
            asm volatile("" ::: "memory");
            f32x4 acc0 = (f32x4){bv0, bv0, bv0, bv0};
            f32x4 acc1 = (f32x4){bv1, bv1, bv1, bv1};
#pragma unroll
            for (int kt = 0; kt < 2; ++kt) {
                acc0 = MFMA16(ua[kt], wcf[0][kt], acc0);
                acc1 = MFMA16(ua[kt], wcf[1][kt], acc1);
            }
            if (t > 0) {
                const _Float16* hp = hx0g + (size_t)((t - 1) & 3) * (16 * H_)
                                   + (size_t)l15 * H_ + kofs;
                half8 a[16];
                ld_frags16_sc(hp, a);
#pragma unroll
                for (int kt = 0; kt < 16; ++kt) {
                    acc0 = MFMA16(a[kt], whf[0][kt], acc0);
                    acc1 = MFMA16(a[kt], whf[1][kt], acc1);
                }
            }
            _Float16* hq = hx0g + (size_t)(t & 3) * (16 * H_);
#pragma unroll
            for (int r = 0; r < 4; ++r) {
                const int m = lg * 4 + r;
                st2c(&hq[(size_t)m * H_ + col0 + l15],      tanh_fast(acc0[r]));
                st2c(&hq[(size_t)m * H_ + col0 + 16 + l15], tanh_fast(acc1[r]));
            }
            asm volatile("s_waitcnt vmcnt(0)" ::: "memory");  // own stores at L3
            __syncthreads();
            if (tid == 0) flag_pub(myflag, t);
        }
    } else if (role < 12) {
        // ================= L1 =================
        const int s = role - 4;
        const int col0 = s * 64 + w * 16;
        const int n = col0 + l15;
        half8 wif[16], whf[16];
#pragma unroll
        for (int kt = 0; kt < 16; ++kt) {
            wif[kt] = *(const half8*)(wih1w + (size_t)n * H_ + kt * 32 + kofs);
            PINH8(wif[kt]);
            whf[kt] = *(const half8*)(whh1w + (size_t)n * H_ + kt * 32 + kofs);
            PINH8(whf[kt]);
        }
        const float bv = b1s[n];
        int* myflag = flags + (32 + g * 8 + s) * FSTR;
        const int* pollp = nullptr; int polld = 0;
        if (tid < 4)        { pollp = flags + (g * 4 + tid) * FSTR;            polld = 0; }
        else if (tid < 12)  { pollp = flags + (32 + g * 8 + (tid - 4)) * FSTR; polld = 1; }
        else if (tid == 12) { pollp = flags + (96 + g) * FSTR;                 polld = 4; }

        for (int t = 0; t < L_; ++t) {
            spin_rel(pollp, t - polld);
            __syncthreads();
            asm volatile("" ::: "memory");
            f32x4 accx = (f32x4){bv, bv, bv, bv};
            f32x4 acch = (f32x4){0.f, 0.f, 0.f, 0.f};
            const _Float16* h0p = hx0g + (size_t)(t & 3) * (16 * H_)
                                + (size_t)l15 * H_ + kofs;
            half8 a0[16], a1[16];
            if (t > 0) {
                const _Float16* h1p = hx1g + (size_t)((t - 1) & 3) * (16 * H_)
                                    + (size_t)l15 * H_ + kofs;
                ld_frags16_sc_nowait(h1p, a1);   // older data: issue first
                ld_frags16_sc(h0p, a0);          // internal vmcnt(0) covers both
                PIN16(a1);                       // bind a1 uses after the wait
#pragma unroll
                for (int kt = 0; kt < 16; ++kt) {
                    accx = MFMA16(a0[kt], wif[kt], accx);
                    acch = MFMA16(a1[kt], whf[kt], acch);
                }
            } else {
                ld_frags16_sc(h0p, a0);
#pragma unroll
                for (int kt = 0; kt < 16; ++kt)
                    accx = MFMA16(a0[kt], wif[kt], accx);
            }
            _Float16* hq = hx1g + (size_t)(t & 3) * (16 * H_);
#pragma unroll
            for (int r = 0; r < 4; ++r)
                st2c(&hq[(size_t)(lg * 4 + r) * H_ + n], tanh_fast(accx[r] + acch[r]));
            asm volatile("s_waitcnt vmcnt(0)" ::: "memory");
            __syncthreads();
            if (tid == 0) flag_pub(myflag, t);
        }
    } else {
        // ================= G3 (output projection) =================
        const int col0 = w * 16;
        const int n = col0 + l15;
        half8 wof[16];
#pragma unroll
        for (int kt = 0; kt < 16; ++kt) {
            wof[kt] = *(const half8*)(woutw + (size_t)n * H_ + kt * 32 + kofs);
            PINH8(wof[kt]);
        }
        int* myflag = flags + (96 + g) * FSTR;
        const int* pollp = (tid < 8) ? flags + (32 + g * 8 + tid) * FSTR : nullptr;

        for (int t = 0; t < L_; ++t) {
            spin_rel(pollp, t);
            __syncthreads();
            asm volatile("" ::: "memory");
            const _Float16* h1p = hx1g + (size_t)(t & 3) * (16 * H_)
                                + (size_t)l15 * H_ + kofs;
            half8 a[16];
            ld_frags16_sc(h1p, a);
            f32x4 acc = (f32x4){0.f, 0.f, 0.f, 0.f};
#pragma unroll
            for (int kt = 0; kt < 16; ++kt)
                acc = MFMA16(a[kt], wof[kt], acc);
            __syncthreads();                       // all h1_t reads complete (asm-internal waits)
            if (tid == 0) flag_pub(myflag, t);     // release slot BEFORE out stores
#pragma unroll
            for (int r = 0; r < 4; ++r)
                out[((size_t)(b0 + lg * 4 + r) * L_ + t) * DOUT + n] = acc[r];
        }
    }
}

// ---------------- launch ----------------
extern "C" void kernel_launch(void* const* d_in, const int* in_sizes, int n_in,
                              void* d_out, int out_size, void* d_ws, size_t ws_size,
                              hipStream_t stream) {
    const float* u    = (const float*)d_in[0];
    const float* Win  = (const float*)d_in[1];
    const float* Wih0 = (const float*)d_in[2];
    const float* Whh0 = (const float*)d_in[3];
    const float* bih0 = (const float*)d_in[4];
    const float* bhh0 = (const float*)d_in[5];
    const float* Wih1 = (const float*)d_in[6];
    const float* Whh1 = (const float*)d_in[7];
    const float* bih1 = (const float*)d_in[8];
    const float* bhh1 = (const float*)d_in[9];
    const float* Wout = (const float*)d_in[10];
    (void)in_sizes; (void)n_in; (void)out_size; (void)ws_size;

    char* ws = (char*)d_ws;
    size_t off = 0;
    auto alloc = [&](size_t bytes) {
        char* p = ws + off;
        off += (bytes + 255) & ~(size_t)255;
        return p;
    };
    // total workspace ~2.7 MB
    _Float16* wcomb = (_Float16*)alloc((size_t)H_ * DIN * 2);
    _Float16* whh0h = (_Float16*)alloc((size_t)H_ * H_ * 2);
    _Float16* wih1h = (_Float16*)alloc((size_t)H_ * H_ * 2);
    _Float16* whh1h = (_Float16*)alloc((size_t)H_ * H_ * 2);
    _Float16* wouth = (_Float16*)alloc((size_t)DOUT * H_ * 2);
    float*    b0s   = (float*)alloc(H_ * 4);
    float*    b1s   = (float*)alloc(H_ * 4);
    _Float16* hx0   = (_Float16*)alloc((size_t)8 * 4 * 16 * H_ * 2);
    _Float16* hx1   = (_Float16*)alloc((size_t)8 * 4 * 16 * H_ * 2);
    int*      flags = (int*)alloc(128 * FSTR * 4);

    k_init_flags<<<1, 128, 0, stream>>>(flags);
    k_prep_w<<<1024, 256, 0, stream>>>(Whh0, Wih1, Whh1, Wout, bih0, bhh0, bih1, bhh1,
                                       whh0h, wih1h, whh1h, wouth, b0s, b1s);
    k_wcomb<<<512, 64, 0, stream>>>(Wih0, Win, wcomb);

    k_pipeline<<<104, 256, 0, stream>>>(u, wcomb, whh0h, b0s, wih1h, whh1h, b1s, wouth,
                                        (float*)d_out, hx0, hx1, flags);
}